// Round 1
// baseline (17031.015 us; speedup 1.0000x reference)
//
#include <hip/hip_runtime.h>
#include <hip/hip_bf16.h>

// Model dims
#define BN 64      // batch
#define TT 192     // total seq
#define ILEN 160   // input_len
#define DIN 8
#define DM 256
#define NH 8
#define DH 32
#define DFF 1024
#define NLAY 4
#define PRE_ROWS (BN * ILEN)   // 10240
#define SCALE 0.17677669529663687f  // 1/sqrt(32)

// ---------------- copy whole_example -> out ----------------
__global__ void copy_out_k(const float* __restrict__ X, float* __restrict__ O, int n) {
    int i = blockIdx.x * blockDim.x + threadIdx.x;
    if (i < n) O[i] = X[i];
}

// ---------------- embedding for prefill rows ----------------
__global__ __launch_bounds__(256) void embed_k(const float* __restrict__ X,
        const float* __restrict__ w, const float* __restrict__ bias,
        float* __restrict__ H) {
    int row = blockIdx.x;            // b*160 + p
    int b = row / ILEN, p = row % ILEN;
    int tid = threadIdx.x;
    const float* x = X + (size_t)(b * TT + p) * DIN;
    float acc = bias[tid];
#pragma unroll
    for (int r = 0; r < DIN; ++r) acc += x[r] * w[r * DM + tid];
    H[(size_t)row * DM + tid] = acc;
}

// ---------------- generic fp32 tiled GEMM: C = A@W + bias (+epilogue) ----------------
// mode: 0 = bias, 1 = bias+relu, 2 = bias+residual(R)
// remap: output row m -> (m/160)*192 + (m%160)  (for KV cache)
__global__ __launch_bounds__(256) void gemm_k(
        const float* __restrict__ A, const float* __restrict__ W,
        const float* __restrict__ bias, const float* __restrict__ R,
        float* __restrict__ C, int M, int N, int K, int mode, int remap) {
    __shared__ float As[16][64];
    __shared__ float Bs[16][64];
    int tid = threadIdx.x;
    int bx = blockIdx.x, by = blockIdx.y;
    int tx = tid & 15, ty = tid >> 4;
    int row0 = by * 64 + ty * 4;
    int col0 = bx * 64 + tx * 4;
    float acc[4][4] = {};
    int arow = tid >> 2, ak4 = tid & 3;
    int brow = tid >> 4, bc4 = tid & 15;
    const float* aptr = A + (size_t)(by * 64 + arow) * K + ak4 * 4;
    const float* bptr = W + (size_t)brow * N + bx * 64 + bc4 * 4;
    for (int kt = 0; kt < K; kt += 16) {
        float4 av = *(const float4*)(aptr + kt);
        float4 bv = *(const float4*)(bptr + (size_t)kt * N);
        As[ak4 * 4 + 0][arow] = av.x;
        As[ak4 * 4 + 1][arow] = av.y;
        As[ak4 * 4 + 2][arow] = av.z;
        As[ak4 * 4 + 3][arow] = av.w;
        *(float4*)&Bs[brow][bc4 * 4] = bv;
        __syncthreads();
#pragma unroll
        for (int k = 0; k < 16; ++k) {
            float a[4], bb[4];
#pragma unroll
            for (int i = 0; i < 4; ++i) a[i] = As[k][ty * 4 + i];
#pragma unroll
            for (int j = 0; j < 4; ++j) bb[j] = Bs[k][tx * 4 + j];
#pragma unroll
            for (int i = 0; i < 4; ++i)
#pragma unroll
                for (int j = 0; j < 4; ++j) acc[i][j] += a[i] * bb[j];
        }
        __syncthreads();
    }
#pragma unroll
    for (int i = 0; i < 4; ++i) {
        int row = row0 + i;
        int orow = remap ? (row / ILEN) * TT + (row % ILEN) : row;
#pragma unroll
        for (int j = 0; j < 4; ++j) {
            int col = col0 + j;
            float v = acc[i][j] + bias[col];
            if (mode == 1) v = fmaxf(v, 0.f);
            if (mode == 2) v += R[(size_t)row * N + col];
            C[(size_t)orow * N + col] = v;
        }
    }
}

// ---------------- prefill attention: one block per (q position, batch) ----------------
__global__ __launch_bounds__(256) void attn_k(
        const float* __restrict__ Q, const float* __restrict__ Kc,
        const float* __restrict__ Vc, float* __restrict__ O) {
    int qp = blockIdx.x;    // 0..159
    int b = blockIdx.y;
    int tid = threadIdx.x;
    int hh = tid >> 5, l = tid & 31;
    __shared__ float qs[DM];
    __shared__ float sc[NH][TT];
    int qrow = b * ILEN + qp;
    qs[tid] = Q[(size_t)qrow * DM + tid] * SCALE;
    __syncthreads();
    const float* Kb = Kc + (size_t)b * TT * DM;
    const float* Vb = Vc + (size_t)b * TT * DM;
    float mx = -1e30f;
    for (int j = l; j <= qp; j += 32) {
        const float* kr = Kb + (size_t)j * DM + hh * DH;
        float d = 0.f;
#pragma unroll
        for (int u = 0; u < DH; ++u) d += qs[hh * DH + u] * kr[u];
        sc[hh][j] = d;
        mx = fmaxf(mx, d);
    }
#pragma unroll
    for (int o = 16; o > 0; o >>= 1) mx = fmaxf(mx, __shfl_xor(mx, o, 32));
    float sum = 0.f;
    for (int j = l; j <= qp; j += 32) {
        float p = __expf(sc[hh][j] - mx);
        sc[hh][j] = p;
        sum += p;
    }
#pragma unroll
    for (int o = 16; o > 0; o >>= 1) sum += __shfl_xor(sum, o, 32);
    float inv = 1.f / sum;
    float acc = 0.f;
    for (int j = 0; j <= qp; ++j)
        acc += sc[hh][j] * Vb[(size_t)j * DM + hh * DH + l];
    O[(size_t)qrow * DM + hh * DH + l] = acc * inv;
}

// ---------------- layernorm over rows of 256 ----------------
__global__ __launch_bounds__(256) void ln_k(const float* __restrict__ Xp,
        const float* __restrict__ g, const float* __restrict__ be,
        float* __restrict__ Y) {
    int row = blockIdx.x;
    int tid = threadIdx.x;
    float x = Xp[(size_t)row * DM + tid];
    float s = x, s2 = x * x;
#pragma unroll
    for (int o = 32; o > 0; o >>= 1) { s += __shfl_xor(s, o); s2 += __shfl_xor(s2, o); }
    __shared__ float red[8];
    if ((tid & 63) == 0) { red[tid >> 6] = s; red[4 + (tid >> 6)] = s2; }
    __syncthreads();
    s = red[0] + red[1] + red[2] + red[3];
    s2 = red[4] + red[5] + red[6] + red[7];
    float m = s * (1.f / 256.f);
    float var = s2 * (1.f / 256.f) - m * m;
    float r = rsqrtf(var + 1e-5f);
    Y[(size_t)row * DM + tid] = (x - m) * r * g[tid] + be[tid];
}

// ---------------- final projection at position 159 -> pred0 ----------------
__global__ __launch_bounds__(256) void final_k(const float* __restrict__ H,
        const float* __restrict__ fw, const float* __restrict__ fb,
        float* __restrict__ out) {
    int b = blockIdx.x;
    int tid = threadIdx.x;
    float v = H[(size_t)(b * ILEN + ILEN - 1) * DM + tid] * fw[tid];
#pragma unroll
    for (int o = 32; o > 0; o >>= 1) v += __shfl_xor(v, o);
    __shared__ float red[4];
    if ((tid & 63) == 0) red[tid >> 6] = v;
    __syncthreads();
    if (tid == 0)
        out[((size_t)b * TT + ILEN) * DIN] = red[0] + red[1] + red[2] + red[3] + fb[0];
}

// ---------------- persistent decode: one block per batch element ----------------
__device__ inline void block_ln(const float* pre, const float* g, const float* be,
                                float* hs, int tid, float* red) {
    float x = pre[tid];
    float s = x, s2 = x * x;
#pragma unroll
    for (int o = 32; o > 0; o >>= 1) { s += __shfl_xor(s, o); s2 += __shfl_xor(s2, o); }
    if ((tid & 63) == 0) { red[tid >> 6] = s; red[4 + (tid >> 6)] = s2; }
    __syncthreads();
    s = red[0] + red[1] + red[2] + red[3];
    s2 = red[4] + red[5] + red[6] + red[7];
    float m = s * (1.f / 256.f);
    float var = s2 * (1.f / 256.f) - m * m;
    float r = rsqrtf(var + 1e-5f);
    hs[tid] = (x - m) * r * g[tid] + be[tid];
}

__global__ __launch_bounds__(256) void decode_k(
        const float* __restrict__ X,
        const float* __restrict__ emb_w, const float* __restrict__ emb_b,
        const float* __restrict__ Wq, const float* __restrict__ bq,
        const float* __restrict__ Wk, const float* __restrict__ bk,
        const float* __restrict__ Wv, const float* __restrict__ bv,
        const float* __restrict__ Wo, const float* __restrict__ bo,
        const float* __restrict__ ln1g, const float* __restrict__ ln1b,
        const float* __restrict__ W1, const float* __restrict__ b1,
        const float* __restrict__ W2, const float* __restrict__ b2,
        const float* __restrict__ ln2g, const float* __restrict__ ln2b,
        const float* __restrict__ fw, const float* __restrict__ fb,
        float* __restrict__ Kc, float* __restrict__ Vc,
        float* __restrict__ out) {
    int b = blockIdx.x;
    int tid = threadIdx.x;
    int hh = tid >> 5, l = tid & 31;
    __shared__ float hs[DM], as_[DM], pre[DM], qs[DM], ffs[DFF];
    __shared__ float sc[NH][TT];
    __shared__ float xs[DIN];
    __shared__ float red[8];
    __shared__ float pred_s;

    if (tid == 0) pred_s = out[((size_t)b * TT + ILEN) * DIN];  // pred0 from prefill

    for (int t = 0; t < TT - ILEN - 1; ++t) {   // 31 steps
        int p = ILEN + t;
        __syncthreads();
        if (tid < DIN)
            xs[tid] = (tid == 0) ? pred_s : X[((size_t)b * TT + p) * DIN + tid];
        __syncthreads();
        // embed
        float h0 = emb_b[tid];
#pragma unroll
        for (int r = 0; r < DIN; ++r) h0 += xs[r] * emb_w[r * DM + tid];
        hs[tid] = h0;
        __syncthreads();

        for (int li = 0; li < NLAY; ++li) {
            const float* wq = Wq + (size_t)li * DM * DM;
            const float* wk = Wk + (size_t)li * DM * DM;
            const float* wv = Wv + (size_t)li * DM * DM;
            const float* wo = Wo + (size_t)li * DM * DM;
            const float* w1 = W1 + (size_t)li * DM * DFF;
            const float* w2 = W2 + (size_t)li * DFF * DM;
            // QKV projections (thread = output dim)
            float aq = bq[li * DM + tid], ak = bk[li * DM + tid], av = bv[li * DM + tid];
#pragma unroll 8
            for (int r = 0; r < DM; ++r) {
                float hv = hs[r];
                aq += hv * wq[r * DM + tid];
                ak += hv * wk[r * DM + tid];
                av += hv * wv[r * DM + tid];
            }
            qs[tid] = aq * SCALE;
            size_t cbase = ((size_t)(li * BN + b) * TT + p) * DM + tid;
            Kc[cbase] = ak;
            Vc[cbase] = av;
            __syncthreads();   // drains global writes; K/V visible to whole block
            // attention over j = 0..p
            const float* Kb = Kc + (size_t)(li * BN + b) * TT * DM;
            const float* Vb = Vc + (size_t)(li * BN + b) * TT * DM;
            float mx = -1e30f;
            for (int j = l; j <= p; j += 32) {
                const float* kr = Kb + (size_t)j * DM + hh * DH;
                float d = 0.f;
#pragma unroll
                for (int u = 0; u < DH; ++u) d += qs[hh * DH + u] * kr[u];
                sc[hh][j] = d;
                mx = fmaxf(mx, d);
            }
#pragma unroll
            for (int o = 16; o > 0; o >>= 1) mx = fmaxf(mx, __shfl_xor(mx, o, 32));
            float sum = 0.f;
            for (int j = l; j <= p; j += 32) {
                float pe = __expf(sc[hh][j] - mx);
                sc[hh][j] = pe;
                sum += pe;
            }
#pragma unroll
            for (int o = 16; o > 0; o >>= 1) sum += __shfl_xor(sum, o, 32);
            float inv = 1.f / sum;
            float acc = 0.f;
            for (int j = 0; j <= p; ++j)
                acc += sc[hh][j] * Vb[(size_t)j * DM + hh * DH + l];
            as_[hh * DH + l] = acc * inv;
            __syncthreads();
            // O projection + residual
            float ov = bo[li * DM + tid] + hs[tid];
#pragma unroll 8
            for (int r = 0; r < DM; ++r) ov += as_[r] * wo[r * DM + tid];
            pre[tid] = ov;
            __syncthreads();
            block_ln(pre, ln1g + li * DM, ln1b + li * DM, hs, tid, red);
            __syncthreads();
            // FFN1 (+relu): each thread 4 hidden dims
            float f0 = b1[li * DFF + tid], f1 = b1[li * DFF + tid + 256];
            float f2 = b1[li * DFF + tid + 512], f3 = b1[li * DFF + tid + 768];
#pragma unroll 8
            for (int r = 0; r < DM; ++r) {
                float hv = hs[r];
                f0 += hv * w1[r * DFF + tid];
                f1 += hv * w1[r * DFF + tid + 256];
                f2 += hv * w1[r * DFF + tid + 512];
                f3 += hv * w1[r * DFF + tid + 768];
            }
            ffs[tid] = fmaxf(f0, 0.f);
            ffs[tid + 256] = fmaxf(f1, 0.f);
            ffs[tid + 512] = fmaxf(f2, 0.f);
            ffs[tid + 768] = fmaxf(f3, 0.f);
            __syncthreads();
            // FFN2 + residual
            float o2 = b2[li * DM + tid] + hs[tid];
#pragma unroll 8
            for (int r = 0; r < DFF; ++r) o2 += ffs[r] * w2[r * DM + tid];
            pre[tid] = o2;
            __syncthreads();
            block_ln(pre, ln2g + li * DM, ln2b + li * DM, hs, tid, red);
            __syncthreads();
        }
        // final projection -> next pred
        float v = hs[tid] * fw[tid];
#pragma unroll
        for (int o = 32; o > 0; o >>= 1) v += __shfl_xor(v, o);
        if ((tid & 63) == 0) red[tid >> 6] = v;
        __syncthreads();
        if (tid == 0) {
            float y = red[0] + red[1] + red[2] + red[3] + fb[0];
            out[((size_t)b * TT + p + 1) * DIN] = y;
            pred_s = y;
        }
    }
}

extern "C" void kernel_launch(void* const* d_in, const int* in_sizes, int n_in,
                              void* d_out, int out_size, void* d_ws, size_t ws_size,
                              hipStream_t stream) {
    const float* X     = (const float*)d_in[0];
    const float* emb_w = (const float*)d_in[1];
    const float* emb_b = (const float*)d_in[2];
    const float* Wq    = (const float*)d_in[3];
    const float* bq    = (const float*)d_in[4];
    const float* Wk    = (const float*)d_in[5];
    const float* bk    = (const float*)d_in[6];
    const float* Wv    = (const float*)d_in[7];
    const float* bv    = (const float*)d_in[8];
    const float* Wo    = (const float*)d_in[9];
    const float* bo    = (const float*)d_in[10];
    const float* ln1g  = (const float*)d_in[11];
    const float* ln1b  = (const float*)d_in[12];
    const float* W1    = (const float*)d_in[13];
    const float* b1    = (const float*)d_in[14];
    const float* W2    = (const float*)d_in[15];
    const float* b2    = (const float*)d_in[16];
    const float* ln2g  = (const float*)d_in[17];
    const float* ln2b  = (const float*)d_in[18];
    const float* fw    = (const float*)d_in[19];
    const float* fb    = (const float*)d_in[20];
    float* out = (float*)d_out;

    // workspace layout (floats)
    float* ws = (float*)d_ws;
    const size_t HROWS = (size_t)PRE_ROWS * DM;        // 2,621,440
    float* h   = ws;
    float* qa  = ws + HROWS;                           // q / attn-out (reused)
    float* pre = ws + 2 * HROWS;
    float* ff  = ws + 3 * HROWS;                       // 10240 x 1024
    float* Kc  = ws + 3 * HROWS + (size_t)PRE_ROWS * DFF;
    float* Vc  = Kc + (size_t)NLAY * BN * TT * DM;
    const size_t LSL = (size_t)BN * TT * DM;           // per-layer cache slice

    copy_out_k<<<(BN * TT * DIN + 255) / 256, 256, 0, stream>>>(X, out, BN * TT * DIN);
    embed_k<<<PRE_ROWS, 256, 0, stream>>>(X, emb_w, emb_b, h);

    for (int li = 0; li < NLAY; ++li) {
        const float* wq = Wq + (size_t)li * DM * DM;
        const float* wk = Wk + (size_t)li * DM * DM;
        const float* wv = Wv + (size_t)li * DM * DM;
        const float* wo = Wo + (size_t)li * DM * DM;
        const float* w1 = W1 + (size_t)li * DM * DFF;
        const float* w2 = W2 + (size_t)li * DFF * DM;
        gemm_k<<<dim3(4, 160), 256, 0, stream>>>(h, wq, bq + li * DM, nullptr, qa,
                                                 PRE_ROWS, DM, DM, 0, 0);
        gemm_k<<<dim3(4, 160), 256, 0, stream>>>(h, wk, bk + li * DM, nullptr, Kc + li * LSL,
                                                 PRE_ROWS, DM, DM, 0, 1);
        gemm_k<<<dim3(4, 160), 256, 0, stream>>>(h, wv, bv + li * DM, nullptr, Vc + li * LSL,
                                                 PRE_ROWS, DM, DM, 0, 1);
        attn_k<<<dim3(ILEN, BN), 256, 0, stream>>>(qa, Kc + li * LSL, Vc + li * LSL, qa);
        gemm_k<<<dim3(4, 160), 256, 0, stream>>>(qa, wo, bo + li * DM, h, pre,
                                                 PRE_ROWS, DM, DM, 2, 0);
        ln_k<<<PRE_ROWS, 256, 0, stream>>>(pre, ln1g + li * DM, ln1b + li * DM, h);
        gemm_k<<<dim3(16, 160), 256, 0, stream>>>(h, w1, b1 + li * DFF, nullptr, ff,
                                                  PRE_ROWS, DFF, DM, 1, 0);
        gemm_k<<<dim3(4, 160), 256, 0, stream>>>(ff, w2, b2 + li * DM, h, pre,
                                                 PRE_ROWS, DM, DFF, 2, 0);
        ln_k<<<PRE_ROWS, 256, 0, stream>>>(pre, ln2g + li * DM, ln2b + li * DM, h);
    }
    final_k<<<BN, 256, 0, stream>>>(h, fw, fb, out);

    decode_k<<<BN, 256, 0, stream>>>(X, emb_w, emb_b, Wq, bq, Wk, bk, Wv, bv, Wo, bo,
                                     ln1g, ln1b, W1, b1, W2, b2, ln2g, ln2b, fw, fb,
                                     Kc, Vc, out);
}